// Round 3
// baseline (436.816 us; speedup 1.0000x reference)
//
#include <hip/hip_runtime.h>
#include <hip/hip_bf16.h>
#include <stdint.h>

// Problem constants (from reference)
#define BSZ   16384
#define INDIM 256
#define HID   1024
#define NA    512
#define NE    4

typedef __hip_bfloat16 bf16;
typedef __attribute__((ext_vector_type(8))) short    short8;
typedef __attribute__((ext_vector_type(4))) float    f32x4;
typedef __attribute__((ext_vector_type(8))) unsigned short u16x8;

// ---------------- async global->LDS (16B per lane) ----------------
// HW semantics: LDS dest = wave-uniform base + lane*16; global src is per-lane.
__device__ __forceinline__ void gload16(const void* g, void* l) {
  __builtin_amdgcn_global_load_lds(
      (__attribute__((address_space(1))) void*)g,
      (__attribute__((address_space(3))) void*)l, 16, 0, 0);
}

// ---------------- small prep kernels ----------------
__global__ void k_zero(int* cnt, int* cursor) {
  if (threadIdx.x < NE) { cnt[threadIdx.x] = 0; cursor[threadIdx.x] = 0; }
}

__global__ void k_count(const float* __restrict__ x, int* __restrict__ cnt) {
  int i = blockIdx.x * blockDim.x + threadIdx.x;
  if (i < BSZ) {
    int r = (int)x[(size_t)i * INDIM + (INDIM - 1)];
    if (r >= 0 && r < NE) atomicAdd(&cnt[r], 1);
  }
}

__global__ void k_prefix(const int* __restrict__ cnt, int* __restrict__ off) {
  if (threadIdx.x == 0) {
    int a = 0;
    for (int e = 0; e < NE; ++e) { off[e] = a; a += cnt[e]; }
  }
}

__global__ void k_scatter(const float* __restrict__ x, const int* __restrict__ off,
                          int* __restrict__ cursor, int* __restrict__ perm) {
  int i = blockIdx.x * blockDim.x + threadIdx.x;
  if (i < BSZ) {
    int r = (int)x[(size_t)i * INDIM + (INDIM - 1)];
    if (r >= 0 && r < NE) {
      int p = atomicAdd(&cursor[r], 1);
      perm[off[r] + p] = i;
    }
  }
}

// fp32 -> bf16 cast, 8 elements/thread (32B read, 16B write)
__global__ void k_cast8(const float* __restrict__ src, bf16* __restrict__ dst, int n8) {
  int i = blockIdx.x * blockDim.x + threadIdx.x;
  if (i >= n8) return;
  const float4* s = (const float4*)src;
  float4 a = s[i * 2], b = s[i * 2 + 1];
  bf16 t[8];
  t[0] = __float2bfloat16(a.x); t[1] = __float2bfloat16(a.y);
  t[2] = __float2bfloat16(a.z); t[3] = __float2bfloat16(a.w);
  t[4] = __float2bfloat16(b.x); t[5] = __float2bfloat16(b.y);
  t[6] = __float2bfloat16(b.z); t[7] = __float2bfloat16(b.w);
  *(u16x8*)(dst + (size_t)i * 8) = *(u16x8*)t;
}

// fp32 [R][C] -> bf16 [C][R], batched on z. grid(C/32, R/32, batch), block(32,8)
__global__ void k_transpose(const float* __restrict__ src, bf16* __restrict__ dst,
                            int R, int C) {
  __shared__ float tile[32][33];
  const float* s = src + (size_t)blockIdx.z * R * C;
  bf16* d = dst + (size_t)blockIdx.z * R * C;
  int c0 = blockIdx.x * 32, r0 = blockIdx.y * 32;
  int tx = threadIdx.x, ty = threadIdx.y;
#pragma unroll
  for (int i = 0; i < 32; i += 8)
    tile[ty + i][tx] = s[(size_t)(r0 + ty + i) * C + c0 + tx];
  __syncthreads();
#pragma unroll
  for (int i = 0; i < 32; i += 8)
    d[(size_t)(c0 + ty + i) * R + r0 + tx] = __float2bfloat16(tile[tx][ty + i]);
}

// ---------------- GEMM: C = relu(A @ Bt^T + bias) -> bf16 ----------------
// A: [M][K] bf16 row-major, Bt: [N][K] bf16 (i.e. B transposed), Out: [M][N] bf16
// 128x128 tile, BK=32, 256 threads (4 waves, 2x2 wave grid, 64x64 per wave)
#define BM 128
#define BN 128
#define BK 32

__global__ __launch_bounds__(256) void k_gemm_relu(
    const bf16* __restrict__ A, const bf16* __restrict__ Bt,
    const float* __restrict__ bias, bf16* __restrict__ Out,
    int M, int N, int K) {
  __shared__ bf16 sA[BM * BK];
  __shared__ bf16 sB[BN * BK];
  const int t = threadIdx.x, w = t >> 6, l = t & 63;
  const int wr = w >> 1, wc = w & 1;
  const int bm0 = blockIdx.y * BM, bn0 = blockIdx.x * BN;
  const int lr = l & 15, lk = (l >> 4) * 8;
  f32x4 acc[4][4] = {};

  for (int k0 = 0; k0 < K; k0 += BK) {
    __syncthreads();  // prior iter's ds_reads done before overwrite
    // slot s covers rows [s*64, s*64+64): 256 thr * 16B = 4096 B per slot
#pragma unroll
    for (int s = 0; s < 2; ++s) {
      const bf16* gA = A + (size_t)(bm0 + s * 64 + (t >> 2)) * K + k0 + (t & 3) * 8;
      gload16(gA, (char*)sA + s * 4096 + w * 1024);
      const bf16* gB = Bt + (size_t)(bn0 + s * 64 + (t >> 2)) * K + k0 + (t & 3) * 8;
      gload16(gB, (char*)sB + s * 4096 + w * 1024);
    }
    __syncthreads();  // barrier drains vmcnt(0) -> staged data visible
    short8 af[4], bfr[4];
#pragma unroll
    for (int m = 0; m < 4; ++m)
      af[m] = *(const short8*)&sA[(wr * 64 + m * 16 + lr) * BK + lk];
#pragma unroll
    for (int n = 0; n < 4; ++n)
      bfr[n] = *(const short8*)&sB[(wc * 64 + n * 16 + lr) * BK + lk];
#pragma unroll
    for (int m = 0; m < 4; ++m)
#pragma unroll
      for (int n = 0; n < 4; ++n)
        acc[m][n] = __builtin_amdgcn_mfma_f32_16x16x32_bf16(af[m], bfr[n], acc[m][n], 0, 0, 0);
  }

#pragma unroll
  for (int m = 0; m < 4; ++m) {
#pragma unroll
    for (int n = 0; n < 4; ++n) {
      int col = bn0 + wc * 64 + n * 16 + lr;
      float bv = bias[col];
#pragma unroll
      for (int r = 0; r < 4; ++r) {
        int row = bm0 + wr * 64 + m * 16 + (l >> 4) * 4 + r;
        float v = acc[m][n][r] + bv;
        v = v > 0.f ? v : 0.f;
        Out[(size_t)row * N + col] = __float2bfloat16(v);
      }
    }
  }
}

// ---------------- GEMM3: per-head gathered rows, softplus+1 epilogue ----------------
// grid: (NA/BN=4, BSZ/BM=128 worst case, NE=4). Blocks beyond head's count exit.
__global__ __launch_bounds__(256) void k_gemm_head(
    const bf16* __restrict__ H, const bf16* __restrict__ Wht,  // [NE][NA][HID]
    const float* __restrict__ bh,                              // [NE][NA]
    const int* __restrict__ perm, const int* __restrict__ cnt,
    const int* __restrict__ off, float* __restrict__ Out) {
  const int e = blockIdx.z;
  const int count = cnt[e];
  const int mstart = blockIdx.y * BM;
  if (mstart >= count) return;
  const int base = off[e];
  const int t = threadIdx.x, w = t >> 6, l = t & 63;
  const int wr = w >> 1, wc = w & 1;
  const int bn0 = blockIdx.x * BN;
  const int lr = l & 15, lk = (l >> 4) * 8;

  __shared__ bf16 sA[BM * BK];
  __shared__ bf16 sB[BN * BK];

  // gathered source rows for this thread's two staging slots (constant over K)
  int srow[2];
#pragma unroll
  for (int s = 0; s < 2; ++s) {
    int ri = mstart + s * 64 + (t >> 2);
    srow[s] = perm[base + (ri < count ? ri : 0)];
  }
  const bf16* Wt = Wht + (size_t)e * NA * HID;
  f32x4 acc[4][4] = {};

  for (int k0 = 0; k0 < HID; k0 += BK) {
    __syncthreads();
#pragma unroll
    for (int s = 0; s < 2; ++s) {
      gload16(H + (size_t)srow[s] * HID + k0 + (t & 3) * 8,
              (char*)sA + s * 4096 + w * 1024);
      gload16(Wt + (size_t)(bn0 + s * 64 + (t >> 2)) * HID + k0 + (t & 3) * 8,
              (char*)sB + s * 4096 + w * 1024);
    }
    __syncthreads();
    short8 af[4], bfr[4];
#pragma unroll
    for (int m = 0; m < 4; ++m)
      af[m] = *(const short8*)&sA[(wr * 64 + m * 16 + lr) * BK + lk];
#pragma unroll
    for (int n = 0; n < 4; ++n)
      bfr[n] = *(const short8*)&sB[(wc * 64 + n * 16 + lr) * BK + lk];
#pragma unroll
    for (int m = 0; m < 4; ++m)
#pragma unroll
      for (int n = 0; n < 4; ++n)
        acc[m][n] = __builtin_amdgcn_mfma_f32_16x16x32_bf16(af[m], bfr[n], acc[m][n], 0, 0, 0);
  }

#pragma unroll
  for (int m = 0; m < 4; ++m) {
#pragma unroll
    for (int r = 0; r < 4; ++r) {
      int lm = wr * 64 + m * 16 + (l >> 4) * 4 + r;
      int ri = mstart + lm;
      if (ri < count) {
        int row = perm[base + ri];
#pragma unroll
        for (int n = 0; n < 4; ++n) {
          int col = bn0 + wc * 64 + n * 16 + lr;
          float v = acc[m][n][r] + bh[e * NA + col];
          float sp = (v > 20.f) ? v : log1pf(expf(v));
          Out[(size_t)row * NA + col] = sp + 1.f;
        }
      }
    }
  }
}

// ---------------- launch ----------------
extern "C" void kernel_launch(void* const* d_in, const int* in_sizes, int n_in,
                              void* d_out, int out_size, void* d_ws, size_t ws_size,
                              hipStream_t stream) {
  const float* x  = (const float*)d_in[0];
  const float* W1 = (const float*)d_in[1];
  const float* b1 = (const float*)d_in[2];
  const float* W2 = (const float*)d_in[3];
  const float* b2 = (const float*)d_in[4];
  const float* Wh = (const float*)d_in[5];
  const float* bh = (const float*)d_in[6];
  float* out = (float*)d_out;

  // workspace carve (all 256B-aligned)
  char* p = (char*)d_ws;
  bf16* xb  = (bf16*)p; p += (size_t)BSZ * INDIM * 2;   // 8 MiB
  bf16* w1t = (bf16*)p; p += (size_t)HID * INDIM * 2;   // 512 KiB
  bf16* w2t = (bf16*)p; p += (size_t)HID * HID * 2;     // 2 MiB
  bf16* wht = (bf16*)p; p += (size_t)NE * NA * HID * 2; // 4 MiB
  bf16* h1b = (bf16*)p; p += (size_t)BSZ * HID * 2;     // 32 MiB
  bf16* h2b = (bf16*)p; p += (size_t)BSZ * HID * 2;     // 32 MiB
  int* perm   = (int*)p; p += (size_t)BSZ * 4;          // 64 KiB
  int* cnt    = (int*)p; p += 256;
  int* off    = (int*)p; p += 256;
  int* cursor = (int*)p; p += 256;

  // routing (counting sort of rows by regime)
  k_zero<<<1, 64, 0, stream>>>(cnt, cursor);
  k_count<<<BSZ / 256, 256, 0, stream>>>(x, cnt);
  k_prefix<<<1, 64, 0, stream>>>(cnt, off);
  k_scatter<<<BSZ / 256, 256, 0, stream>>>(x, off, cursor, perm);

  // bf16 conversions
  k_cast8<<<(BSZ * INDIM / 8 + 255) / 256, 256, 0, stream>>>(x, xb, BSZ * INDIM / 8);
  k_transpose<<<dim3(HID / 32, INDIM / 32, 1), dim3(32, 8), 0, stream>>>(W1, w1t, INDIM, HID);
  k_transpose<<<dim3(HID / 32, HID / 32, 1), dim3(32, 8), 0, stream>>>(W2, w2t, HID, HID);
  k_transpose<<<dim3(NA / 32, HID / 32, NE), dim3(32, 8), 0, stream>>>(Wh, wht, HID, NA);

  // GEMM1: h1 = relu(x @ W1 + b1)
  k_gemm_relu<<<dim3(HID / BN, BSZ / BM), 256, 0, stream>>>(xb, w1t, b1, h1b,
                                                            BSZ, HID, INDIM);
  // GEMM2: h2 = relu(h1 @ W2 + b2)
  k_gemm_relu<<<dim3(HID / BN, BSZ / BM), 256, 0, stream>>>(h1b, w2t, b2, h2b,
                                                            BSZ, HID, HID);
  // GEMM3: per-head, gathered rows, softplus+1
  k_gemm_head<<<dim3(NA / BN, BSZ / BM, NE), 256, 0, stream>>>(h2b, wht, bh,
                                                               perm, cnt, off, out);
}

// Round 4
// 262.813 us; speedup vs baseline: 1.6621x; 1.6621x over previous
//
#include <hip/hip_runtime.h>
#include <hip/hip_bf16.h>
#include <stdint.h>

// Problem constants (from reference)
#define BSZ   16384
#define INDIM 256
#define HID   1024
#define NA    512
#define NE    4

typedef __hip_bfloat16 bf16;
typedef __attribute__((ext_vector_type(8))) short    short8;
typedef __attribute__((ext_vector_type(4))) float    f32x4;
typedef __attribute__((ext_vector_type(8))) unsigned short u16x8;

// ---------------- async global->LDS (16B per lane) ----------------
// HW semantics: LDS dest = wave-uniform base + lane*16; global src is per-lane.
__device__ __forceinline__ void gload16(const void* g, void* l) {
  __builtin_amdgcn_global_load_lds(
      (__attribute__((address_space(1))) void*)g,
      (__attribute__((address_space(3))) void*)l, 16, 0, 0);
}

// ---------------- small prep kernels ----------------
__global__ void k_zero(int* cnt, int* cursor) {
  if (threadIdx.x < NE) { cnt[threadIdx.x] = 0; cursor[threadIdx.x] = 0; }
}

// per-block LDS histogram -> 4 global atomics per block (was 256)
__global__ void k_count(const float* __restrict__ x, int* __restrict__ cnt) {
  __shared__ int h[NE];
  const int t = threadIdx.x;
  if (t < NE) h[t] = 0;
  __syncthreads();
  int i = blockIdx.x * blockDim.x + t;
  int r = (int)x[(size_t)i * INDIM + (INDIM - 1)];
  if (r >= 0 && r < NE) atomicAdd(&h[r], 1);
  __syncthreads();
  if (t < NE && h[t] > 0) atomicAdd(&cnt[t], h[t]);
}

__global__ void k_prefix(const int* __restrict__ cnt, int* __restrict__ off) {
  if (threadIdx.x == 0) {
    int a = 0;
    for (int e = 0; e < NE; ++e) { off[e] = a; a += cnt[e]; }
  }
}

// block claims a contiguous chunk per regime; in-block rank via LDS atomics
__global__ void k_scatter(const float* __restrict__ x, const int* __restrict__ off,
                          int* __restrict__ cursor, int* __restrict__ perm) {
  __shared__ int h[NE], base[NE];
  const int t = threadIdx.x;
  if (t < NE) h[t] = 0;
  __syncthreads();
  int i = blockIdx.x * blockDim.x + t;
  int r = (int)x[(size_t)i * INDIM + (INDIM - 1)];
  int lrank = -1;
  if (r >= 0 && r < NE) lrank = atomicAdd(&h[r], 1);
  __syncthreads();
  if (t < NE) base[t] = (h[t] > 0) ? atomicAdd(&cursor[t], h[t]) : 0;
  __syncthreads();
  if (r >= 0 && r < NE) perm[off[r] + base[r] + lrank] = i;
}

// fp32 -> bf16 cast, 8 elements/thread (32B read, 16B write)
__global__ void k_cast8(const float* __restrict__ src, bf16* __restrict__ dst, int n8) {
  int i = blockIdx.x * blockDim.x + threadIdx.x;
  if (i >= n8) return;
  const float4* s = (const float4*)src;
  float4 a = s[i * 2], b = s[i * 2 + 1];
  bf16 t[8];
  t[0] = __float2bfloat16(a.x); t[1] = __float2bfloat16(a.y);
  t[2] = __float2bfloat16(a.z); t[3] = __float2bfloat16(a.w);
  t[4] = __float2bfloat16(b.x); t[5] = __float2bfloat16(b.y);
  t[6] = __float2bfloat16(b.z); t[7] = __float2bfloat16(b.w);
  *(u16x8*)(dst + (size_t)i * 8) = *(u16x8*)t;
}

// fp32 [R][C] -> bf16 [C][R], batched on z. grid(C/32, R/32, batch), block(32,8)
__global__ void k_transpose(const float* __restrict__ src, bf16* __restrict__ dst,
                            int R, int C) {
  __shared__ float tile[32][33];
  const float* s = src + (size_t)blockIdx.z * R * C;
  bf16* d = dst + (size_t)blockIdx.z * R * C;
  int c0 = blockIdx.x * 32, r0 = blockIdx.y * 32;
  int tx = threadIdx.x, ty = threadIdx.y;
#pragma unroll
  for (int i = 0; i < 32; i += 8)
    tile[ty + i][tx] = s[(size_t)(r0 + ty + i) * C + c0 + tx];
  __syncthreads();
#pragma unroll
  for (int i = 0; i < 32; i += 8)
    d[(size_t)(c0 + ty + i) * R + r0 + tx] = __float2bfloat16(tile[tx][ty + i]);
}

// ---------------- GEMM: C = relu(A @ Bt^T + bias) -> bf16 ----------------
// A: [M][K] bf16 row-major, Bt: [N][K] bf16 (i.e. B transposed), Out: [M][N] bf16
// 128x128 tile, BK=32, 256 threads (4 waves, 2x2 wave grid, 64x64 per wave)
#define BM 128
#define BN 128
#define BK 32

__global__ __launch_bounds__(256) void k_gemm_relu(
    const bf16* __restrict__ A, const bf16* __restrict__ Bt,
    const float* __restrict__ bias, bf16* __restrict__ Out,
    int M, int N, int K) {
  __shared__ bf16 sA[BM * BK];
  __shared__ bf16 sB[BN * BK];
  const int t = threadIdx.x, w = t >> 6, l = t & 63;
  const int wr = w >> 1, wc = w & 1;
  const int bm0 = blockIdx.y * BM, bn0 = blockIdx.x * BN;
  const int lr = l & 15, lk = (l >> 4) * 8;
  f32x4 acc[4][4] = {};

  for (int k0 = 0; k0 < K; k0 += BK) {
    __syncthreads();  // prior iter's ds_reads done before overwrite
    // slot s covers rows [s*64, s*64+64): 256 thr * 16B = 4096 B per slot
#pragma unroll
    for (int s = 0; s < 2; ++s) {
      const bf16* gA = A + (size_t)(bm0 + s * 64 + (t >> 2)) * K + k0 + (t & 3) * 8;
      gload16(gA, (char*)sA + s * 4096 + w * 1024);
      const bf16* gB = Bt + (size_t)(bn0 + s * 64 + (t >> 2)) * K + k0 + (t & 3) * 8;
      gload16(gB, (char*)sB + s * 4096 + w * 1024);
    }
    __syncthreads();  // barrier drains vmcnt(0) -> staged data visible
    short8 af[4], bfr[4];
#pragma unroll
    for (int m = 0; m < 4; ++m)
      af[m] = *(const short8*)&sA[(wr * 64 + m * 16 + lr) * BK + lk];
#pragma unroll
    for (int n = 0; n < 4; ++n)
      bfr[n] = *(const short8*)&sB[(wc * 64 + n * 16 + lr) * BK + lk];
#pragma unroll
    for (int m = 0; m < 4; ++m)
#pragma unroll
      for (int n = 0; n < 4; ++n)
        acc[m][n] = __builtin_amdgcn_mfma_f32_16x16x32_bf16(af[m], bfr[n], acc[m][n], 0, 0, 0);
  }

#pragma unroll
  for (int m = 0; m < 4; ++m) {
#pragma unroll
    for (int n = 0; n < 4; ++n) {
      int col = bn0 + wc * 64 + n * 16 + lr;
      float bv = bias[col];
#pragma unroll
      for (int r = 0; r < 4; ++r) {
        int row = bm0 + wr * 64 + m * 16 + (l >> 4) * 4 + r;
        float v = acc[m][n][r] + bv;
        v = v > 0.f ? v : 0.f;
        Out[(size_t)row * N + col] = __float2bfloat16(v);
      }
    }
  }
}

// ---------------- GEMM3: per-head gathered rows, softplus+1 epilogue ----------------
// grid: (NA/BN=4, BSZ/BM=128 worst case, NE=4). Blocks beyond head's count exit.
__global__ __launch_bounds__(256) void k_gemm_head(
    const bf16* __restrict__ H, const bf16* __restrict__ Wht,  // [NE][NA][HID]
    const float* __restrict__ bh,                              // [NE][NA]
    const int* __restrict__ perm, const int* __restrict__ cnt,
    const int* __restrict__ off, float* __restrict__ Out) {
  const int e = blockIdx.z;
  const int count = cnt[e];
  const int mstart = blockIdx.y * BM;
  if (mstart >= count) return;
  const int base = off[e];
  const int t = threadIdx.x, w = t >> 6, l = t & 63;
  const int wr = w >> 1, wc = w & 1;
  const int bn0 = blockIdx.x * BN;
  const int lr = l & 15, lk = (l >> 4) * 8;

  __shared__ bf16 sA[BM * BK];
  __shared__ bf16 sB[BN * BK];

  // gathered source rows for this thread's two staging slots (constant over K)
  int srow[2];
#pragma unroll
  for (int s = 0; s < 2; ++s) {
    int ri = mstart + s * 64 + (t >> 2);
    srow[s] = perm[base + (ri < count ? ri : 0)];
  }
  const bf16* Wt = Wht + (size_t)e * NA * HID;
  f32x4 acc[4][4] = {};

  for (int k0 = 0; k0 < HID; k0 += BK) {
    __syncthreads();
#pragma unroll
    for (int s = 0; s < 2; ++s) {
      gload16(H + (size_t)srow[s] * HID + k0 + (t & 3) * 8,
              (char*)sA + s * 4096 + w * 1024);
      gload16(Wt + (size_t)(bn0 + s * 64 + (t >> 2)) * HID + k0 + (t & 3) * 8,
              (char*)sB + s * 4096 + w * 1024);
    }
    __syncthreads();
    short8 af[4], bfr[4];
#pragma unroll
    for (int m = 0; m < 4; ++m)
      af[m] = *(const short8*)&sA[(wr * 64 + m * 16 + lr) * BK + lk];
#pragma unroll
    for (int n = 0; n < 4; ++n)
      bfr[n] = *(const short8*)&sB[(wc * 64 + n * 16 + lr) * BK + lk];
#pragma unroll
    for (int m = 0; m < 4; ++m)
#pragma unroll
      for (int n = 0; n < 4; ++n)
        acc[m][n] = __builtin_amdgcn_mfma_f32_16x16x32_bf16(af[m], bfr[n], acc[m][n], 0, 0, 0);
  }

#pragma unroll
  for (int m = 0; m < 4; ++m) {
#pragma unroll
    for (int r = 0; r < 4; ++r) {
      int lm = wr * 64 + m * 16 + (l >> 4) * 4 + r;
      int ri = mstart + lm;
      if (ri < count) {
        int row = perm[base + ri];
#pragma unroll
        for (int n = 0; n < 4; ++n) {
          int col = bn0 + wc * 64 + n * 16 + lr;
          float v = acc[m][n][r] + bh[e * NA + col];
          float sp = (v > 20.f) ? v : log1pf(expf(v));
          Out[(size_t)row * NA + col] = sp + 1.f;
        }
      }
    }
  }
}

// ---------------- launch ----------------
extern "C" void kernel_launch(void* const* d_in, const int* in_sizes, int n_in,
                              void* d_out, int out_size, void* d_ws, size_t ws_size,
                              hipStream_t stream) {
  const float* x  = (const float*)d_in[0];
  const float* W1 = (const float*)d_in[1];
  const float* b1 = (const float*)d_in[2];
  const float* W2 = (const float*)d_in[3];
  const float* b2 = (const float*)d_in[4];
  const float* Wh = (const float*)d_in[5];
  const float* bh = (const float*)d_in[6];
  float* out = (float*)d_out;

  // workspace carve (all 256B-aligned)
  char* p = (char*)d_ws;
  bf16* xb  = (bf16*)p; p += (size_t)BSZ * INDIM * 2;   // 8 MiB
  bf16* w1t = (bf16*)p; p += (size_t)HID * INDIM * 2;   // 512 KiB
  bf16* w2t = (bf16*)p; p += (size_t)HID * HID * 2;     // 2 MiB
  bf16* wht = (bf16*)p; p += (size_t)NE * NA * HID * 2; // 4 MiB
  bf16* h1b = (bf16*)p; p += (size_t)BSZ * HID * 2;     // 32 MiB
  bf16* h2b = (bf16*)p; p += (size_t)BSZ * HID * 2;     // 32 MiB
  int* perm   = (int*)p; p += (size_t)BSZ * 4;          // 64 KiB
  int* cnt    = (int*)p; p += 256;
  int* off    = (int*)p; p += 256;
  int* cursor = (int*)p; p += 256;

  // routing (counting sort of rows by regime, hierarchical histogram)
  k_zero<<<1, 64, 0, stream>>>(cnt, cursor);
  k_count<<<BSZ / 256, 256, 0, stream>>>(x, cnt);
  k_prefix<<<1, 64, 0, stream>>>(cnt, off);
  k_scatter<<<BSZ / 256, 256, 0, stream>>>(x, off, cursor, perm);

  // bf16 conversions
  k_cast8<<<(BSZ * INDIM / 8 + 255) / 256, 256, 0, stream>>>(x, xb, BSZ * INDIM / 8);
  k_transpose<<<dim3(HID / 32, INDIM / 32, 1), dim3(32, 8), 0, stream>>>(W1, w1t, INDIM, HID);
  k_transpose<<<dim3(HID / 32, HID / 32, 1), dim3(32, 8), 0, stream>>>(W2, w2t, HID, HID);
  k_transpose<<<dim3(NA / 32, HID / 32, NE), dim3(32, 8), 0, stream>>>(Wh, wht, HID, NA);

  // GEMM1: h1 = relu(x @ W1 + b1)
  k_gemm_relu<<<dim3(HID / BN, BSZ / BM), 256, 0, stream>>>(xb, w1t, b1, h1b,
                                                            BSZ, HID, INDIM);
  // GEMM2: h2 = relu(h1 @ W2 + b2)
  k_gemm_relu<<<dim3(HID / BN, BSZ / BM), 256, 0, stream>>>(h1b, w2t, b2, h2b,
                                                            BSZ, HID, HID);
  // GEMM3: per-head, gathered rows, softplus+1
  k_gemm_head<<<dim3(NA / BN, BSZ / BM, NE), 256, 0, stream>>>(h2b, wht, bh,
                                                               perm, cnt, off, out);
}

// Round 5
// 261.035 us; speedup vs baseline: 1.6734x; 1.0068x over previous
//
#include <hip/hip_runtime.h>
#include <hip/hip_bf16.h>
#include <stdint.h>

// Problem constants (from reference)
#define BSZ   16384
#define INDIM 256
#define HID   1024
#define NA    512
#define NE    4
#define BM 128
#define BN 128
#define BK 32
// padded-sorted row space: each head segment 128-aligned
#define PADM (BSZ + NE * BM)   // 16896

typedef __hip_bfloat16 bf16;
typedef __attribute__((ext_vector_type(8))) short    short8;
typedef __attribute__((ext_vector_type(4))) float    f32x4;
typedef __attribute__((ext_vector_type(8))) unsigned short u16x8;

// ---------------- async global->LDS (16B per lane) ----------------
// HW semantics: LDS dest = wave-uniform base + lane*16; global src is per-lane.
__device__ __forceinline__ void gload16(const void* g, void* l) {
  __builtin_amdgcn_global_load_lds(
      (__attribute__((address_space(1))) void*)g,
      (__attribute__((address_space(3))) void*)l, 16, 0, 0);
}

// ---------------- routing ----------------
__global__ void k_zero(int* cnt, int* cursor) {
  if (threadIdx.x < NE) { cnt[threadIdx.x] = 0; cursor[threadIdx.x] = 0; }
}

// per-block LDS histogram -> 4 global atomics per block
__global__ void k_count(const float* __restrict__ x, int* __restrict__ cnt) {
  __shared__ int h[NE];
  const int t = threadIdx.x;
  if (t < NE) h[t] = 0;
  __syncthreads();
  int i = blockIdx.x * blockDim.x + t;
  int r = (int)x[(size_t)i * INDIM + (INDIM - 1)];
  if (r >= 0 && r < NE) atomicAdd(&h[r], 1);
  __syncthreads();
  if (t < NE && h[t] > 0) atomicAdd(&cnt[t], h[t]);
}

// padded prefix: segment e starts at poff[e], size ceil(cnt/BM)*BM; poff[NE]=total
__global__ void k_prefix(const int* __restrict__ cnt, int* __restrict__ poff) {
  if (threadIdx.x == 0) {
    int a = 0;
    for (int e = 0; e < NE; ++e) {
      poff[e] = a;
      a += (cnt[e] + BM - 1) / BM * BM;
    }
    poff[NE] = a;
  }
}

// block claims contiguous chunk per regime; emits both directions of the perm
__global__ void k_scatter(const float* __restrict__ x, const int* __restrict__ poff,
                          int* __restrict__ cursor, int* __restrict__ sortidx,
                          int* __restrict__ rowid) {
  __shared__ int h[NE], base[NE];
  const int t = threadIdx.x;
  if (t < NE) h[t] = 0;
  __syncthreads();
  int i = blockIdx.x * blockDim.x + t;
  int r = (int)x[(size_t)i * INDIM + (INDIM - 1)];
  int lrank = -1;
  if (r >= 0 && r < NE) lrank = atomicAdd(&h[r], 1);
  __syncthreads();
  if (t < NE) base[t] = (h[t] > 0) ? atomicAdd(&cursor[t], h[t]) : 0;
  __syncthreads();
  if (r >= 0 && r < NE) {
    int p = poff[r] + base[r] + lrank;
    sortidx[i] = p;
    rowid[p] = i;
  }
}

// fp32 -> bf16 cast INTO PERMUTED ROW ORDER. 8 cols/thread; 32 consecutive
// threads share a row -> writes are contiguous 512B segments per row.
__global__ void k_cast_perm(const float* __restrict__ x, const int* __restrict__ sortidx,
                            bf16* __restrict__ xb) {
  int i = blockIdx.x * blockDim.x + threadIdx.x;   // [0, BSZ*INDIM/8)
  int row = i >> 5, c8 = (i & 31) * 8;
  int drow = sortidx[row];
  const float4* s = (const float4*)(x + (size_t)row * INDIM + c8);
  float4 a = s[0], b = s[1];
  bf16 t[8];
  t[0] = __float2bfloat16(a.x); t[1] = __float2bfloat16(a.y);
  t[2] = __float2bfloat16(a.z); t[3] = __float2bfloat16(a.w);
  t[4] = __float2bfloat16(b.x); t[5] = __float2bfloat16(b.y);
  t[6] = __float2bfloat16(b.z); t[7] = __float2bfloat16(b.w);
  *(u16x8*)(xb + (size_t)drow * INDIM + c8) = *(u16x8*)t;
}

// fp32 [R][C] -> bf16 [C][R], batched on z. grid(C/32, R/32, batch), block(32,8)
__global__ void k_transpose(const float* __restrict__ src, bf16* __restrict__ dst,
                            int R, int C) {
  __shared__ float tile[32][33];
  const float* s = src + (size_t)blockIdx.z * R * C;
  bf16* d = dst + (size_t)blockIdx.z * R * C;
  int c0 = blockIdx.x * 32, r0 = blockIdx.y * 32;
  int tx = threadIdx.x, ty = threadIdx.y;
#pragma unroll
  for (int i = 0; i < 32; i += 8)
    tile[ty + i][tx] = s[(size_t)(r0 + ty + i) * C + c0 + tx];
  __syncthreads();
#pragma unroll
  for (int i = 0; i < 32; i += 8)
    d[(size_t)(c0 + ty + i) * R + r0 + tx] = __float2bfloat16(tile[tx][ty + i]);
}

// ---------------- GEMM: C = relu(A @ Bt^T + bias) -> bf16 ----------------
// A: [M][K] bf16 row-major (padded-sorted), Bt: [N][K] bf16, Out: [M][N] bf16
// 128x128 tile, BK=32, 256 threads (4 waves, 2x2), dense coalesced staging.
__global__ __launch_bounds__(256) void k_gemm_relu(
    const bf16* __restrict__ A, const bf16* __restrict__ Bt,
    const float* __restrict__ bias, bf16* __restrict__ Out,
    int N, int K) {
  __shared__ bf16 sA[BM * BK];
  __shared__ bf16 sB[BN * BK];
  const int t = threadIdx.x, w = t >> 6, l = t & 63;
  const int wr = w >> 1, wc = w & 1;
  const int bm0 = blockIdx.y * BM, bn0 = blockIdx.x * BN;
  const int lr = l & 15, lk = (l >> 4) * 8;
  f32x4 acc[4][4] = {};

  for (int k0 = 0; k0 < K; k0 += BK) {
    __syncthreads();
#pragma unroll
    for (int s = 0; s < 2; ++s) {
      gload16(A + (size_t)(bm0 + s * 64 + (t >> 2)) * K + k0 + (t & 3) * 8,
              (char*)sA + s * 4096 + w * 1024);
      gload16(Bt + (size_t)(bn0 + s * 64 + (t >> 2)) * K + k0 + (t & 3) * 8,
              (char*)sB + s * 4096 + w * 1024);
    }
    __syncthreads();
    short8 af[4], bfr[4];
#pragma unroll
    for (int m = 0; m < 4; ++m)
      af[m] = *(const short8*)&sA[(wr * 64 + m * 16 + lr) * BK + lk];
#pragma unroll
    for (int n = 0; n < 4; ++n)
      bfr[n] = *(const short8*)&sB[(wc * 64 + n * 16 + lr) * BK + lk];
#pragma unroll
    for (int m = 0; m < 4; ++m)
#pragma unroll
      for (int n = 0; n < 4; ++n)
        acc[m][n] = __builtin_amdgcn_mfma_f32_16x16x32_bf16(af[m], bfr[n], acc[m][n], 0, 0, 0);
  }

#pragma unroll
  for (int m = 0; m < 4; ++m) {
#pragma unroll
    for (int n = 0; n < 4; ++n) {
      int col = bn0 + wc * 64 + n * 16 + lr;
      float bv = bias[col];
#pragma unroll
      for (int r = 0; r < 4; ++r) {
        int row = bm0 + wr * 64 + m * 16 + (l >> 4) * 4 + r;
        float v = acc[m][n][r] + bv;
        v = v > 0.f ? v : 0.f;
        Out[(size_t)row * N + col] = __float2bfloat16(v);
      }
    }
  }
}

// ---------------- GEMM3: dense per-head GEMM on padded-sorted rows ----------------
// grid (NA/BN=4, PADM/BM=132). Head derived from poff; softplus+1; scatter store.
__global__ __launch_bounds__(256) void k_gemm_head(
    const bf16* __restrict__ H,      // [PADM][HID] padded-sorted
    const bf16* __restrict__ Wht,    // [NE][NA][HID]
    const float* __restrict__ bh,    // [NE][NA]
    const int* __restrict__ poff,    // [NE+1]
    const int* __restrict__ cnt,     // [NE]
    const int* __restrict__ rowid,   // [PADM]
    float* __restrict__ Out) {
  const int mb0 = blockIdx.y * BM;
  if (mb0 >= poff[NE]) return;
  int e = 0;
#pragma unroll
  for (int k = 1; k < NE; ++k) if (mb0 >= poff[k]) e = k;
  const int pend = poff[e] + cnt[e];   // rows >= pend are padding

  const int t = threadIdx.x, w = t >> 6, l = t & 63;
  const int wr = w >> 1, wc = w & 1;
  const int bn0 = blockIdx.x * BN;
  const int lr = l & 15, lk = (l >> 4) * 8;
  const bf16* Wt = Wht + (size_t)e * NA * HID;

  __shared__ bf16 sA[BM * BK];
  __shared__ bf16 sB[BN * BK];
  f32x4 acc[4][4] = {};

  for (int k0 = 0; k0 < HID; k0 += BK) {
    __syncthreads();
#pragma unroll
    for (int s = 0; s < 2; ++s) {
      gload16(H + (size_t)(mb0 + s * 64 + (t >> 2)) * HID + k0 + (t & 3) * 8,
              (char*)sA + s * 4096 + w * 1024);
      gload16(Wt + (size_t)(bn0 + s * 64 + (t >> 2)) * HID + k0 + (t & 3) * 8,
              (char*)sB + s * 4096 + w * 1024);
    }
    __syncthreads();
    short8 af[4], bfr[4];
#pragma unroll
    for (int m = 0; m < 4; ++m)
      af[m] = *(const short8*)&sA[(wr * 64 + m * 16 + lr) * BK + lk];
#pragma unroll
    for (int n = 0; n < 4; ++n)
      bfr[n] = *(const short8*)&sB[(wc * 64 + n * 16 + lr) * BK + lk];
#pragma unroll
    for (int m = 0; m < 4; ++m)
#pragma unroll
      for (int n = 0; n < 4; ++n)
        acc[m][n] = __builtin_amdgcn_mfma_f32_16x16x32_bf16(af[m], bfr[n], acc[m][n], 0, 0, 0);
  }

#pragma unroll
  for (int m = 0; m < 4; ++m) {
#pragma unroll
    for (int r = 0; r < 4; ++r) {
      int ps = mb0 + wr * 64 + m * 16 + (l >> 4) * 4 + r;
      if (ps < pend) {
        int row = rowid[ps];
#pragma unroll
        for (int n = 0; n < 4; ++n) {
          int col = bn0 + wc * 64 + n * 16 + lr;
          float v = acc[m][n][r] + bh[e * NA + col];
          float sp = (v > 20.f) ? v : log1pf(expf(v));
          Out[(size_t)row * NA + col] = sp + 1.f;
        }
      }
    }
  }
}

// ---------------- launch ----------------
extern "C" void kernel_launch(void* const* d_in, const int* in_sizes, int n_in,
                              void* d_out, int out_size, void* d_ws, size_t ws_size,
                              hipStream_t stream) {
  const float* x  = (const float*)d_in[0];
  const float* W1 = (const float*)d_in[1];
  const float* b1 = (const float*)d_in[2];
  const float* W2 = (const float*)d_in[3];
  const float* b2 = (const float*)d_in[4];
  const float* Wh = (const float*)d_in[5];
  const float* bh = (const float*)d_in[6];
  float* out = (float*)d_out;

  // workspace carve (all 256B-aligned)
  char* p = (char*)d_ws;
  bf16* xb  = (bf16*)p; p += (size_t)PADM * INDIM * 2;  // 8.7 MiB (permuted)
  bf16* w1t = (bf16*)p; p += (size_t)HID * INDIM * 2;   // 512 KiB
  bf16* w2t = (bf16*)p; p += (size_t)HID * HID * 2;     // 2 MiB
  bf16* wht = (bf16*)p; p += (size_t)NE * NA * HID * 2; // 4 MiB
  bf16* h1b = (bf16*)p; p += (size_t)PADM * HID * 2;    // 34.6 MiB (permuted)
  bf16* h2b = (bf16*)p; p += (size_t)PADM * HID * 2;    // 34.6 MiB (permuted)
  int* sortidx = (int*)p; p += (size_t)BSZ * 4;         // orig -> padded pos
  int* rowid   = (int*)p; p += (size_t)PADM * 4;        // padded pos -> orig
  int* cnt    = (int*)p; p += 256;
  int* poff   = (int*)p; p += 256;
  int* cursor = (int*)p; p += 256;

  const int MB = PADM / BM;  // 132 m-blocks over padded row space

  // routing (counting sort of rows by regime, hierarchical histogram)
  k_zero<<<1, 64, 0, stream>>>(cnt, cursor);
  k_count<<<BSZ / 256, 256, 0, stream>>>(x, cnt);
  k_prefix<<<1, 64, 0, stream>>>(cnt, poff);
  k_scatter<<<BSZ / 256, 256, 0, stream>>>(x, poff, cursor, sortidx, rowid);

  // bf16 conversions (x cast lands in permuted row order)
  k_cast_perm<<<BSZ * (INDIM / 8) / 256, 256, 0, stream>>>(x, sortidx, xb);
  k_transpose<<<dim3(HID / 32, INDIM / 32, 1), dim3(32, 8), 0, stream>>>(W1, w1t, INDIM, HID);
  k_transpose<<<dim3(HID / 32, HID / 32, 1), dim3(32, 8), 0, stream>>>(W2, w2t, HID, HID);
  k_transpose<<<dim3(NA / 32, HID / 32, NE), dim3(32, 8), 0, stream>>>(Wh, wht, HID, NA);

  // GEMM1: h1 = relu(xs @ W1 + b1)   (padded rows compute garbage, masked later)
  k_gemm_relu<<<dim3(HID / BN, MB), 256, 0, stream>>>(xb, w1t, b1, h1b, HID, INDIM);
  // GEMM2: h2 = relu(h1 @ W2 + b2)
  k_gemm_relu<<<dim3(HID / BN, MB), 256, 0, stream>>>(h1b, w2t, b2, h2b, HID, HID);
  // GEMM3: dense per-head, softplus+1, scatter store via rowid
  k_gemm_head<<<dim3(NA / BN, MB), 256, 0, stream>>>(h2b, wht, bh, poff, cnt, rowid, out);
}